// Round 2
// baseline (1449.954 us; speedup 1.0000x reference)
//
#include <hip/hip_runtime.h>
#include <hip/hip_fp16.h>
#include <math.h>

static constexpr float NEGF = -1e30f;
static constexpr float CLAMPF = 3.8918202981106265f; // -log(1/0.98 - 1)
static constexpr float SCALEF = 0.125f;              // 1/sqrt(64)

// ---------------------------------------------------------------------------
// GEMM  C = A * B^T (+epilogue). A: MxK (lda), B: NxK (ldb), C: MxN (ldc)
// Batched over blockIdx.z: b = z/hdiv, h = z%hdiv; per-operand (b,h) strides
// (C strides are in C's element type). Tiles: 128x128, BK=8, 256 thr, 8x8/thr.
// EPI: 0 = f32 +bias, 1 = fp16 tanh(x)*CLAMP, 2 = f32 x*SCALE
// ---------------------------------------------------------------------------
template<int EPI>
__global__ __launch_bounds__(256)
void gemm_nt_k(const float* __restrict__ Ag, const float* __restrict__ Bg,
               void* __restrict__ Cg, const float* __restrict__ bias,
               int M, int N, int K, int lda, int ldb, int ldc,
               long sAb, long sAh, long sBb, long sBh, long sCb, long sCh,
               int hdiv)
{
    __shared__ float As[8][128];
    __shared__ float Bs[8][128];
    int z = blockIdx.z;
    int b = z / hdiv, h = z % hdiv;
    const float* A = Ag + (long)b * sAb + (long)h * sAh;
    const float* B = Bg + (long)b * sBb + (long)h * sBh;

    int tid = threadIdx.x;
    int bm = blockIdx.y * 128, bn = blockIdx.x * 128;
    int tm = (tid >> 4) * 8, tn = (tid & 15) * 8;
    int lrow = tid >> 1, lcol = (tid & 1) * 4;

    float acc[8][8];
#pragma unroll
    for (int i = 0; i < 8; ++i)
#pragma unroll
        for (int j = 0; j < 8; ++j) acc[i][j] = 0.f;

    const float* aptr = A + (long)(bm + lrow) * lda + lcol;
    const float* bptr = B + (long)(bn + lrow) * ldb + lcol;

    for (int kt = 0; kt < K; kt += 8) {
        float4 av = *(const float4*)(aptr + kt);
        float4 bv = *(const float4*)(bptr + kt);
        __syncthreads();
        As[lcol + 0][lrow] = av.x; As[lcol + 1][lrow] = av.y;
        As[lcol + 2][lrow] = av.z; As[lcol + 3][lrow] = av.w;
        Bs[lcol + 0][lrow] = bv.x; Bs[lcol + 1][lrow] = bv.y;
        Bs[lcol + 2][lrow] = bv.z; Bs[lcol + 3][lrow] = bv.w;
        __syncthreads();
#pragma unroll
        for (int k = 0; k < 8; ++k) {
            float a[8], bw[8];
            *(float4*)(a + 0)  = *(const float4*)&As[k][tm];
            *(float4*)(a + 4)  = *(const float4*)&As[k][tm + 4];
            *(float4*)(bw + 0) = *(const float4*)&Bs[k][tn];
            *(float4*)(bw + 4) = *(const float4*)&Bs[k][tn + 4];
#pragma unroll
            for (int i = 0; i < 8; ++i)
#pragma unroll
                for (int j = 0; j < 8; ++j)
                    acc[i][j] = fmaf(a[i], bw[j], acc[i][j]);
        }
    }

    if constexpr (EPI == 1) {
        __half* C = (__half*)Cg + (long)b * sCb + (long)h * sCh;
#pragma unroll
        for (int i = 0; i < 8; ++i) {
            long row = bm + tm + i;
            __half2* cp = (__half2*)(C + row * (long)ldc + bn + tn);
#pragma unroll
            for (int j = 0; j < 4; ++j) {
                float x0 = tanhf(acc[i][2 * j + 0]) * CLAMPF;
                float x1 = tanhf(acc[i][2 * j + 1]) * CLAMPF;
                cp[j] = __floats2half2_rn(x0, x1);
            }
        }
    } else {
        float* C = (float*)Cg + (long)b * sCb + (long)h * sCh;
#pragma unroll
        for (int i = 0; i < 8; ++i) {
            long row = bm + tm + i;
            float* cp = C + row * (long)ldc + bn + tn;
#pragma unroll
            for (int j0 = 0; j0 < 8; j0 += 4) {
                float vv[4];
#pragma unroll
                for (int j = 0; j < 4; ++j) {
                    float x = acc[i][j0 + j];
                    if (EPI == 0) { if (bias) x += bias[bn + tn + j0 + j]; }
                    else { x *= SCALEF; }
                    vv[j] = x;
                }
                float4 v; v.x = vv[0]; v.y = vv[1]; v.z = vv[2]; v.w = vv[3];
                *(float4*)(cp + j0) = v;
            }
        }
    }
}

// ---------------------------------------------------------------------------
// GEMM  C = A * B  (A: MxK lda, B: KxN ldb, C: MxN ldc), 64x64 tiles, BK=16.
// Used for PV: per (b,h): P(128x1024) @ V(1024x64).
// ---------------------------------------------------------------------------
__global__ __launch_bounds__(256)
void gemm_nn64_k(const float* __restrict__ Ag, const float* __restrict__ Bg,
                 float* __restrict__ Cg,
                 int M, int N, int K, int lda, int ldb, int ldc,
                 long sAb, long sAh, long sBb, long sBh, long sCb, long sCh,
                 int hdiv)
{
    __shared__ float As[16][64];
    __shared__ float Bs[16][64];
    int z = blockIdx.z;
    int b = z / hdiv, h = z % hdiv;
    const float* A = Ag + (long)b * sAb + (long)h * sAh;
    const float* B = Bg + (long)b * sBb + (long)h * sBh;
    float* C = Cg + (long)b * sCb + (long)h * sCh;

    int tid = threadIdx.x;
    int bm = blockIdx.y * 64, bn = blockIdx.x * 64;
    int tm = (tid >> 4) * 4, tn = (tid & 15) * 4;
    int arow = tid >> 2, acol = (tid & 3) * 4;
    int brow = tid >> 4, bcol = (tid & 15) * 4;

    float acc[4][4];
#pragma unroll
    for (int i = 0; i < 4; ++i)
#pragma unroll
        for (int j = 0; j < 4; ++j) acc[i][j] = 0.f;

    for (int kt = 0; kt < K; kt += 16) {
        float4 av = *(const float4*)(A + (long)(bm + arow) * lda + kt + acol);
        float4 bv = *(const float4*)(B + (long)(kt + brow) * ldb + bn + bcol);
        __syncthreads();
        As[acol + 0][arow] = av.x; As[acol + 1][arow] = av.y;
        As[acol + 2][arow] = av.z; As[acol + 3][arow] = av.w;
        *(float4*)&Bs[brow][bcol] = bv;
        __syncthreads();
#pragma unroll
        for (int k = 0; k < 16; ++k) {
            float a[4], bw[4];
            *(float4*)a  = *(const float4*)&As[k][tm];
            *(float4*)bw = *(const float4*)&Bs[k][tn];
#pragma unroll
            for (int i = 0; i < 4; ++i)
#pragma unroll
                for (int j = 0; j < 4; ++j)
                    acc[i][j] = fmaf(a[i], bw[j], acc[i][j]);
        }
    }

#pragma unroll
    for (int i = 0; i < 4; ++i) {
        float* cp = C + (long)(bm + tm + i) * ldc + bn + tn;
        float4 v; v.x = acc[i][0]; v.y = acc[i][1]; v.z = acc[i][2]; v.w = acc[i][3];
        *(float4*)cp = v;
    }
}

// ---------------------------------------------------------------------------
// Monotonic alignment DP (log space), one block per (b,h) slice, IN-PLACE on
// the fp16 phi buffer (phi col j is consumed before alpha col j overwrites it).
// Layout (n, q, k): column q contiguous in k (this is ref-phi transposed).
// alpha[k][q] = LAE(alpha[k][q-1]+ls(phi[k][q-1]), alpha[k-1][q-1]+ls(-phi[k-1][q-1]))
// 256 threads x 4 rows each; shift-by-one via shfl_up + LDS wave boundary.
// ---------------------------------------------------------------------------
__device__ __forceinline__ float lae_(float a, float b) {
    float mx = fmaxf(a, b);
    float d = fabsf(a - b);
    return mx + __logf(1.f + __expf(-d));
}

__global__ __launch_bounds__(256)
void mono_dp_k(__half* __restrict__ PA)
{
    int n = blockIdx.x;
    int t = threadIdx.x;
    __half* base = PA + (long)n * (512L * 1024);
    __shared__ float bound[2][4];
    int wave = t >> 6, lane = t & 63;
    int i0 = t * 4;

    __half2* p0 = (__half2*)(base + i0);
    __half2 h01 = p0[0], h23 = p0[1];
    float2 f01 = __half22float2(h01), f23 = __half22float2(h23);
    float pcx = f01.x, pcy = f01.y, pcz = f23.x, pcw = f23.y;

    float al0 = (t == 0) ? 0.f : NEGF, al1 = NEGF, al2 = NEGF, al3 = NEGF;
    p0[0] = __floats2half2_rn(al0, al1);   // after the load above
    p0[1] = __floats2half2_rn(al2, al3);

    for (int j = 1; j < 512; ++j) {
        __half2* pj = (__half2*)(base + (long)j * 1024 + i0);
        __half2 n01 = pj[0], n23 = pj[1];   // phi col j (before overwrite)

        float lp0, lp1, lp2, lp3, l10, l11, l12, l13;
        { float x = pcx; float l = __logf(1.f + __expf(-fabsf(x)));
          lp0 = fminf(x, 0.f) - l; l10 = fminf(-x, 0.f) - l; }
        { float x = pcy; float l = __logf(1.f + __expf(-fabsf(x)));
          lp1 = fminf(x, 0.f) - l; l11 = fminf(-x, 0.f) - l; }
        { float x = pcz; float l = __logf(1.f + __expf(-fabsf(x)));
          lp2 = fminf(x, 0.f) - l; l12 = fminf(-x, 0.f) - l; }
        { float x = pcw; float l = __logf(1.f + __expf(-fabsf(x)));
          lp3 = fminf(x, 0.f) - l; l13 = fminf(-x, 0.f) - l; }

        float mtop = al3 + l13;                 // row i0+3 feeds next thread's row i0
        float ms = __shfl_up(mtop, 1, 64);
        if (lane == 63) bound[j & 1][wave] = mtop;
        __syncthreads();
        if (lane == 0) ms = (wave == 0) ? NEGF : bound[j & 1][wave - 1];

        float m1 = al0 + l10, m2 = al1 + l11, m3 = al2 + l12;
        al0 = lae_(al0 + lp0, ms);
        al1 = lae_(al1 + lp1, m1);
        al2 = lae_(al2 + lp2, m2);
        al3 = lae_(al3 + lp3, m3);

        pj[0] = __floats2half2_rn(al0, al1);    // alpha col j over phi col j
        pj[1] = __floats2half2_rn(al2, al3);

        float2 g01 = __half22float2(n01), g23 = __half22float2(n23);
        pcx = g01.x; pcy = g01.y; pcz = g23.x; pcw = g23.y;
    }
}

// ---------------------------------------------------------------------------
// Row softmax over k: P = softmax(reg + alpha) in-place on reg chunk.
// Chunked over q: row = n*128 + ql; alpha row = (n, q0+ql). 1 block/row.
// ---------------------------------------------------------------------------
__global__ __launch_bounds__(256)
void softmax_pk_k(float* __restrict__ P, const __half* __restrict__ ALPHA, int q0)
{
    int row = blockIdx.x;             // [0, 64*128)
    int n = row >> 7, ql = row & 127;
    float* rp = P + (long)row * 1024;
    const __half* ap = ALPHA + (long)n * (512L * 1024) + (long)(q0 + ql) * 1024;
    int t = threadIdx.x;

    float4 r = ((const float4*)rp)[t];
    const __half2* ah = (const __half2*)ap + t * 2;
    float2 a01 = __half22float2(ah[0]);
    float2 a23 = __half22float2(ah[1]);
    float v0 = r.x + a01.x, v1 = r.y + a01.y, v2 = r.z + a23.x, v3 = r.w + a23.y;

    float mx = fmaxf(fmaxf(v0, v1), fmaxf(v2, v3));
#pragma unroll
    for (int o = 1; o < 64; o <<= 1) mx = fmaxf(mx, __shfl_xor(mx, o, 64));
    __shared__ float redm[4], reds[4];
    int wave = t >> 6, lane = t & 63;
    if (lane == 0) redm[wave] = mx;
    __syncthreads();
    mx = fmaxf(fmaxf(redm[0], redm[1]), fmaxf(redm[2], redm[3]));

    float e0 = __expf(v0 - mx), e1 = __expf(v1 - mx);
    float e2 = __expf(v2 - mx), e3 = __expf(v3 - mx);
    float s = e0 + e1 + e2 + e3;
#pragma unroll
    for (int o = 1; o < 64; o <<= 1) s += __shfl_xor(s, o, 64);
    if (lane == 0) reds[wave] = s;
    __syncthreads();
    s = reds[0] + reds[1] + reds[2] + reds[3];
    float inv = 1.f / s;
    float4 o4; o4.x = e0 * inv; o4.y = e1 * inv; o4.z = e2 * inv; o4.w = e3 * inv;
    ((float4*)rp)[t] = o4;
}

// ---------------------------------------------------------------------------
extern "C" void kernel_launch(void* const* d_in, const int* in_sizes, int n_in,
                              void* d_out, int out_size, void* d_ws, size_t ws_size,
                              hipStream_t stream)
{
    const float* q   = (const float*)d_in[0];
    const float* key = (const float*)d_in[1];
    const float* val = (const float*)d_in[2];
    const float* W   = (const float*)d_in[3];
    const float* ipb = (const float*)d_in[4];
    const float* ow  = (const float*)d_in[5];
    const float* ob  = (const float*)d_in[6];
    float* out = (float*)d_out;
    float* ws  = (float*)d_ws;

    // Workspace (floats unless noted). Total: 148.5 MB.
    float*  XQA  = ws;                           // 2048 x 1024   (8 MB)
    float*  XQ   = XQA + 2097152;                // 2048 x 1024   (8 MB)
    float*  XK   = XQ + 2097152;                 // 4096 x 1024   (16 MB)
    float*  XV   = XK + 4194304;                 // 4096 x 1024   (16 MB)
    __half* PHIA = (__half*)(XV + 4194304);      // (64,512,1024) fp16 (67 MB), phi -> alpha in-place
    float*  REGC = (float*)(PHIA + 33554432);    // (64,128,1024) f32 chunk (33.5 MB)
    float*  XO   = XQA;                          // overlay: XQA dead after phi GEMM

    dim3 blk(256);

    // Projections (f32 + bias)
    gemm_nt_k<0><<<dim3(8, 16, 1), blk, 0, stream>>>(
        q, W, XQA, ipb, 2048, 1024, 1024, 1024, 1024, 1024, 0, 0, 0, 0, 0, 0, 1);
    gemm_nt_k<0><<<dim3(8, 16, 1), blk, 0, stream>>>(
        q, W + 1048576, XQ, ipb + 1024, 2048, 1024, 1024, 1024, 1024, 1024, 0, 0, 0, 0, 0, 0, 1);
    gemm_nt_k<0><<<dim3(8, 32, 1), blk, 0, stream>>>(
        key, W + 2097152, XK, ipb + 2048, 4096, 1024, 1024, 1024, 1024, 1024, 0, 0, 0, 0, 0, 0, 1);
    gemm_nt_k<0><<<dim3(8, 32, 1), blk, 0, stream>>>(
        val, W + 3145728, XV, ipb + 3072, 4096, 1024, 1024, 1024, 1024, 1024, 0, 0, 0, 0, 0, 0, 1);

    // phi[n][q][k] = tanh(xqa_q . xk_k) * CLAMP  -> fp16
    gemm_nt_k<1><<<dim3(8, 4, 64), blk, 0, stream>>>(
        XQA, XK, PHIA, nullptr, 512, 1024, 64, 1024, 1024, 1024,
        512L * 1024, 64, 1024L * 1024, 64, 8388608L, 524288L, 16);

    // monotonic DP in-place (phi -> alpha)
    mono_dp_k<<<dim3(64), blk, 0, stream>>>(PHIA);

    // chunked over q (128 rows/chunk): reg -> softmax(+alpha) -> PV
    for (int qc = 0; qc < 4; ++qc) {
        const float* Aq = XQ + (long)qc * 131072;
        gemm_nt_k<2><<<dim3(8, 1, 64), blk, 0, stream>>>(
            Aq, XK, REGC, nullptr, 128, 1024, 64, 1024, 1024, 1024,
            512L * 1024, 64, 1024L * 1024, 64, 2097152L, 131072L, 16);
        softmax_pk_k<<<dim3(8192), blk, 0, stream>>>(REGC, PHIA, qc * 128);
        gemm_nn64_k<<<dim3(1, 2, 64), blk, 0, stream>>>(
            REGC, XV, XO + (long)qc * 131072, 128, 64, 1024, 1024, 1024, 1024,
            2097152L, 131072L, 1048576L, 64, 524288L, 64, 16);
    }

    // out projection: (2048x1024)@(1024x1024)^T + ob
    gemm_nt_k<0><<<dim3(8, 16, 1), blk, 0, stream>>>(
        XO, ow, out, ob, 2048, 1024, 1024, 1024, 1024, 1024, 0, 0, 0, 0, 0, 0, 1);
}

// Round 3
// 547.611 us; speedup vs baseline: 2.6478x; 2.6478x over previous
//
#include <hip/hip_runtime.h>
#include <hip/hip_fp16.h>
#include <hip/hip_bf16.h>
#include <math.h>

typedef unsigned short u16;
typedef __attribute__((ext_vector_type(8))) short bf16x8;
typedef __attribute__((ext_vector_type(8))) unsigned short u16x8;
typedef __attribute__((ext_vector_type(4))) unsigned short u16x4;
typedef __attribute__((ext_vector_type(4))) float f32x4;

static constexpr float NEGF = -1e30f;
static constexpr float CLAMPF = 3.8918202981106265f; // -log(1/0.98 - 1)
static constexpr float SCALEF = 0.125f;              // 1/sqrt(64)

__device__ __forceinline__ u16 f2bf(float x) {
    __hip_bfloat16 h = __float2bfloat16(x);
    return *reinterpret_cast<u16*>(&h);
}
__device__ __forceinline__ float bf2f(u16 b) {
    unsigned int u = ((unsigned int)b) << 16;
    return __uint_as_float(u);
}

// ---------------------------------------------------------------------------
// f32 -> bf16 conversion (vectorized 4/thread)
// ---------------------------------------------------------------------------
__global__ __launch_bounds__(256)
void cvt_f32_bf16_k(const float* __restrict__ src, u16* __restrict__ dst, int n4)
{
    int i = blockIdx.x * 256 + threadIdx.x;
    if (i < n4) {
        float4 v = ((const float4*)src)[i];
        u16x4 o; o.x = f2bf(v.x); o.y = f2bf(v.y); o.z = f2bf(v.z); o.w = f2bf(v.w);
        ((u16x4*)dst)[i] = o;
    }
}

// ---------------------------------------------------------------------------
// bf16 MFMA GEMM, NT form: C[m][n] = sum_k A[m][k]*B[n][k]  (+ epilogue)
// Tile TM x TN, BK=64, 256 threads = 4 waves in 2x2 grid, mfma_f32_16x16x32_bf16.
// Fragment layouts (m89-verified): A/B lane l: idx=l&15, k=(l>>4)*8+j;
// C/D lane l: col=l&15, row=(l>>4)*4+reg.
// Batched over blockIdx.z: b=z/hdiv, h=z%hdiv, per-operand strides (elements).
// EPI: 0=bf16(+opt bias), 1=fp16 tanh*CLAMP, 2=bf16 *SCALE, 3=f32+bias,
//      4=bf16 V-transpose store (VT[(b*16+h)*64+d][k]) + bias
// ---------------------------------------------------------------------------
template<int TM, int TN, int EPI>
__global__ __launch_bounds__(256)
void mfma_nt(const u16* __restrict__ Ag, const u16* __restrict__ Bg,
             void* __restrict__ Cg, const float* __restrict__ bias,
             int K, int lda, int ldb, int ldc,
             long sAb, long sAh, long sBb, long sBh, long sCb, long sCh,
             int hdiv)
{
    __shared__ u16 As[TM * 64];
    __shared__ u16 Bs[TN * 64];

    int z = blockIdx.z;
    int b = z / hdiv, h = z % hdiv;
    const u16* A = Ag + (long)b * sAb + (long)h * sAh;
    const u16* B = Bg + (long)b * sBb + (long)h * sBh;

    int tid = threadIdx.x;
    int bm = blockIdx.y * TM, bn = blockIdx.x * TN;

    constexpr int AC = TM / 32;   // 16B-load rounds for A tile
    constexpr int BC = TN / 32;
    int srow = tid >> 3;          // 0..31
    int scol = (tid & 7) * 8;     // 0..56

    int wid = tid >> 6, lane = tid & 63;
    int wr = wid >> 1, wc = wid & 1;
    constexpr int MI = TM / 32;   // frags per wave (m)
    constexpr int NI = TN / 32;
    int arow0 = wr * (TM / 2) + (lane & 15);
    int bcol0 = wc * (TN / 2) + (lane & 15);
    int koff = (lane >> 4) * 8;

    f32x4 acc[MI][NI];
#pragma unroll
    for (int i = 0; i < MI; ++i)
#pragma unroll
        for (int j = 0; j < NI; ++j) acc[i][j] = (f32x4){0.f, 0.f, 0.f, 0.f};

    for (int kt = 0; kt < K; kt += 64) {
        u16x8 av[AC], bv[BC];
#pragma unroll
        for (int c = 0; c < AC; ++c)
            av[c] = *(const u16x8*)(A + (long)(bm + srow + 32 * c) * lda + kt + scol);
#pragma unroll
        for (int c = 0; c < BC; ++c)
            bv[c] = *(const u16x8*)(B + (long)(bn + srow + 32 * c) * ldb + kt + scol);
        __syncthreads();
#pragma unroll
        for (int c = 0; c < AC; ++c)
            *(u16x8*)&As[(srow + 32 * c) * 64 + scol] = av[c];
#pragma unroll
        for (int c = 0; c < BC; ++c)
            *(u16x8*)&Bs[(srow + 32 * c) * 64 + scol] = bv[c];
        __syncthreads();

#pragma unroll
        for (int ks = 0; ks < 2; ++ks) {
            bf16x8 af[MI], bfr[NI];
#pragma unroll
            for (int mi = 0; mi < MI; ++mi)
                af[mi] = *(const bf16x8*)&As[(arow0 + 16 * mi) * 64 + ks * 32 + koff];
#pragma unroll
            for (int ni = 0; ni < NI; ++ni)
                bfr[ni] = *(const bf16x8*)&Bs[(bcol0 + 16 * ni) * 64 + ks * 32 + koff];
#pragma unroll
            for (int mi = 0; mi < MI; ++mi)
#pragma unroll
                for (int ni = 0; ni < NI; ++ni)
                    acc[mi][ni] = __builtin_amdgcn_mfma_f32_16x16x32_bf16(
                        af[mi], bfr[ni], acc[mi][ni], 0, 0, 0);
        }
    }

    // Epilogue
    int rbase = bm + wr * (TM / 2) + (lane >> 4) * 4;
    int cbase = bn + wc * (TN / 2) + (lane & 15);
#pragma unroll
    for (int mi = 0; mi < MI; ++mi) {
#pragma unroll
        for (int ni = 0; ni < NI; ++ni) {
            int m0 = rbase + 16 * mi;
            int n = cbase + 16 * ni;
            if constexpr (EPI == 0) {
                u16* C = (u16*)Cg + (long)b * sCb + (long)h * sCh;
                float bvv = bias ? bias[n] : 0.f;
#pragma unroll
                for (int r = 0; r < 4; ++r)
                    C[(long)(m0 + r) * ldc + n] = f2bf(acc[mi][ni][r] + bvv);
            } else if constexpr (EPI == 1) {
                __half* C = (__half*)Cg + (long)b * sCb + (long)h * sCh;
#pragma unroll
                for (int r = 0; r < 4; ++r)
                    C[(long)(m0 + r) * ldc + n] = __float2half(tanhf(acc[mi][ni][r]) * CLAMPF);
            } else if constexpr (EPI == 2) {
                u16* C = (u16*)Cg + (long)b * sCb + (long)h * sCh;
#pragma unroll
                for (int r = 0; r < 4; ++r)
                    C[(long)(m0 + r) * ldc + n] = f2bf(acc[mi][ni][r] * SCALEF);
            } else if constexpr (EPI == 3) {
                float* C = (float*)Cg + (long)b * sCb + (long)h * sCh;
                float bvv = bias[n];
#pragma unroll
                for (int r = 0; r < 4; ++r)
                    C[(long)(m0 + r) * ldc + n] = acc[mi][ni][r] + bvv;
            } else { // EPI == 4: VT[(b16h)*64 + d][k] = V[m=b*1024+k][n=h*64+d]
                u16* C = (u16*)Cg;
                float bvv = bias[n];
                long vaddr = ((long)((m0 >> 10) * 16 + (n >> 6)) * 64 + (n & 63)) * 1024
                             + (m0 & 1023);
                u16x4 pk;
                pk.x = f2bf(acc[mi][ni][0] + bvv);
                pk.y = f2bf(acc[mi][ni][1] + bvv);
                pk.z = f2bf(acc[mi][ni][2] + bvv);
                pk.w = f2bf(acc[mi][ni][3] + bvv);
                *(u16x4*)(C + vaddr) = pk;
            }
        }
    }
}

// ---------------------------------------------------------------------------
// Monotonic DP chunk: alpha cols [q0, q0+128) from phi (separate buffers).
// One block per (b,h) slice; 256 thr x 4 rows; raw s_barrier (no vmcnt drain);
// prefetch depth 4 with statically-named registers.
// ---------------------------------------------------------------------------
__device__ __forceinline__ float lae_(float a, float b) {
    float mx = fmaxf(a, b);
    float d = fabsf(a - b);
    return mx + __logf(1.f + __expf(-d));
}

#define DP_LOAD(J) (*(const uint2*)(phi + (long)min((J), 511) * 1024 + i0))

#define DP_STEP(PC) do { \
    __half2 _h01 = *(__half2*)&(PC).x, _h23 = *(__half2*)&(PC).y; \
    float2 _f01 = __half22float2(_h01), _f23 = __half22float2(_h23); \
    float lp0, lp1, lp2, lp3, l10, l11, l12, l13; \
    { float x = _f01.x; float l = __logf(1.f + __expf(-fabsf(x))); lp0 = fminf(x, 0.f) - l; l10 = fminf(-x, 0.f) - l; } \
    { float x = _f01.y; float l = __logf(1.f + __expf(-fabsf(x))); lp1 = fminf(x, 0.f) - l; l11 = fminf(-x, 0.f) - l; } \
    { float x = _f23.x; float l = __logf(1.f + __expf(-fabsf(x))); lp2 = fminf(x, 0.f) - l; l12 = fminf(-x, 0.f) - l; } \
    { float x = _f23.y; float l = __logf(1.f + __expf(-fabsf(x))); lp3 = fminf(x, 0.f) - l; l13 = fminf(-x, 0.f) - l; } \
    float mtop = a3 + l13; \
    float ms = __shfl_up(mtop, 1, 64); \
    if (lane == 63) bound[j & 1][wave] = mtop; \
    asm volatile("s_waitcnt lgkmcnt(0)" ::: "memory"); \
    __builtin_amdgcn_s_barrier(); \
    __builtin_amdgcn_sched_barrier(0); \
    if (lane == 0) ms = (wave == 0) ? NEGF : bound[j & 1][wave - 1]; \
    float m1 = a0 + l10, m2 = a1 + l11, m3 = a2 + l12; \
    a0 = lae_(a0 + lp0, ms); a1 = lae_(a1 + lp1, m1); \
    a2 = lae_(a2 + lp2, m2); a3 = lae_(a3 + lp3, m3); \
    __half2 _o01 = __floats2half2_rn(a0, a1), _o23 = __floats2half2_rn(a2, a3); \
    uint2 _st; _st.x = *(unsigned*)&_o01; _st.y = *(unsigned*)&_o23; \
    *(uint2*)(al + (long)(j - q0) * 1024 + i0) = _st; \
} while (0)

__global__ __launch_bounds__(256)
void mono_dp_k(const __half* __restrict__ PHI, __half* __restrict__ AL,
               float* __restrict__ STATE, int q0)
{
    int n = blockIdx.x;
    int t = threadIdx.x;
    const __half* phi = PHI + (long)n * 524288;
    __half* al = AL + (long)n * 131072;
    float* stt = STATE + (long)n * 1024;
    __shared__ float bound[2][4];
    int wave = t >> 6, lane = t & 63;
    int i0 = t * 4;

    float a0, a1, a2, a3;
    if (q0 == 0) {
        a0 = (t == 0) ? 0.f : NEGF; a1 = NEGF; a2 = NEGF; a3 = NEGF;
        __half2 h01 = __floats2half2_rn(a0, a1), h23 = __floats2half2_rn(a2, a3);
        uint2 st; st.x = *(unsigned*)&h01; st.y = *(unsigned*)&h23;
        *(uint2*)(al + i0) = st;   // alpha column 0 = init
    } else {
        float4 s = *(const float4*)(stt + i0);
        a0 = s.x; a1 = s.y; a2 = s.z; a3 = s.w;
    }

    int jbeg = (q0 == 0) ? 1 : q0;
    int jend = q0 + 128;
    uint2 pA = DP_LOAD(jbeg - 1);
    uint2 pB = DP_LOAD(jbeg + 0);
    uint2 pC = DP_LOAD(jbeg + 1);
    uint2 pD = DP_LOAD(jbeg + 2);

    int j = jbeg;
    int nmain = ((jend - jbeg) >> 2) << 2;
    for (int g = 0; g < nmain; g += 4) {
        DP_STEP(pA); pA = DP_LOAD(j + 3); ++j;
        DP_STEP(pB); pB = DP_LOAD(j + 3); ++j;
        DP_STEP(pC); pC = DP_LOAD(j + 3); ++j;
        DP_STEP(pD); pD = DP_LOAD(j + 3); ++j;
    }
    for (; j < jend; ++j) {
        DP_STEP(pA);
        pA = pB; pB = pC; pC = pD;
    }

    float4 s; s.x = a0; s.y = a1; s.z = a2; s.w = a3;
    *(float4*)(stt + i0) = s;
}

// ---------------------------------------------------------------------------
// Row softmax over k: P = softmax(scores + alpha), bf16 in/out, alpha fp16.
// Row-linear chunk layout: both (64,128,1024), row = blockIdx.x.
// ---------------------------------------------------------------------------
__global__ __launch_bounds__(256)
void softmax_pk_k(u16* __restrict__ P, const __half* __restrict__ A)
{
    long row = blockIdx.x;
    u16* rp = P + (row << 10);
    const __half* ap = A + (row << 10);
    int t = threadIdx.x;

    u16x4 s4 = ((const u16x4*)rp)[t];
    uint2 au = ((const uint2*)ap)[t];
    __half2 a01 = *(__half2*)&au.x, a23 = *(__half2*)&au.y;
    float2 fa01 = __half22float2(a01), fa23 = __half22float2(a23);
    float v0 = bf2f(s4.x) + fa01.x, v1 = bf2f(s4.y) + fa01.y;
    float v2 = bf2f(s4.z) + fa23.x, v3 = bf2f(s4.w) + fa23.y;

    float mx = fmaxf(fmaxf(v0, v1), fmaxf(v2, v3));
#pragma unroll
    for (int o = 1; o < 64; o <<= 1) mx = fmaxf(mx, __shfl_xor(mx, o, 64));
    __shared__ float redm[4], reds[4];
    int wave = t >> 6, lane = t & 63;
    if (lane == 0) redm[wave] = mx;
    __syncthreads();
    mx = fmaxf(fmaxf(redm[0], redm[1]), fmaxf(redm[2], redm[3]));

    float e0 = __expf(v0 - mx), e1 = __expf(v1 - mx);
    float e2 = __expf(v2 - mx), e3 = __expf(v3 - mx);
    float s = e0 + e1 + e2 + e3;
#pragma unroll
    for (int o = 1; o < 64; o <<= 1) s += __shfl_xor(s, o, 64);
    if (lane == 0) reds[wave] = s;
    __syncthreads();
    s = reds[0] + reds[1] + reds[2] + reds[3];
    float inv = 1.f / s;
    u16x4 o4; o4.x = f2bf(e0 * inv); o4.y = f2bf(e1 * inv);
    o4.z = f2bf(e2 * inv); o4.w = f2bf(e3 * inv);
    ((u16x4*)rp)[t] = o4;
}

// ---------------------------------------------------------------------------
extern "C" void kernel_launch(void* const* d_in, const int* in_sizes, int n_in,
                              void* d_out, int out_size, void* d_ws, size_t ws_size,
                              hipStream_t stream)
{
    const float* q   = (const float*)d_in[0];
    const float* key = (const float*)d_in[1];
    const float* val = (const float*)d_in[2];
    const float* W   = (const float*)d_in[3];
    const float* ipb = (const float*)d_in[4];
    const float* ow  = (const float*)d_in[5];
    const float* ob  = (const float*)d_in[6];
    float* out = (float*)d_out;
    char* w = (char*)d_ws;

    // Workspace layout (bytes). Total 126.25 MiB.
    __half* PHI    = (__half*)(w);                 // 64 MiB  (64,512,1024) fp16
    __half* ALPHAC = (__half*)(w + 67108864);      // 16 MiB  (64,128,1024) fp16
    float*  STATE  = (float*)(w + 83886080);       // 256 KiB (64,1024) f32
    u16*    XQAQ   = (u16*)(w + 84148224);         // 8 MiB   (2048,2048) bf16
    u16*    XK     = (u16*)(w + 92536832);         // 8 MiB   (4096,1024) bf16
    u16*    VT     = (u16*)(w + 100925440);        // 8 MiB   (64,64,1024) bf16
    u16*    REGC   = (u16*)(w + 109314048);        // 16 MiB  (64,128,1024) bf16
    u16*    XO     = (u16*)(w + 126091264);        // 4 MiB   (2048,1024) bf16
    u16*    OWBF   = (u16*)(w + 130285568);        // 2 MiB   (1024,1024) bf16
    // Overlays inside PHI region (dead before phi GEMM writes):
    u16* QBF = (u16*)(w);                          // 4 MiB
    u16* KBF = (u16*)(w + 4194304);                // 8 MiB
    u16* VBF = (u16*)(w + 12582912);               // 8 MiB
    u16* WBF = (u16*)(w + 20971520);               // 8 MiB

    dim3 blk(256);

    // 0) f32 -> bf16 copies
    cvt_f32_bf16_k<<<dim3(2048), blk, 0, stream>>>(q, QBF, 524288);
    cvt_f32_bf16_k<<<dim3(4096), blk, 0, stream>>>(key, KBF, 1048576);
    cvt_f32_bf16_k<<<dim3(4096), blk, 0, stream>>>(val, VBF, 1048576);
    cvt_f32_bf16_k<<<dim3(4096), blk, 0, stream>>>(W, WBF, 1048576);
    cvt_f32_bf16_k<<<dim3(1024), blk, 0, stream>>>(ow, OWBF, 262144);

    // 1) XQAQ = q @ W[0:2048]^T + ipb[0:2048]  (cols 0..1023 = xqa, 1024.. = xq)
    mfma_nt<128, 128, 0><<<dim3(16, 16, 1), blk, 0, stream>>>(
        QBF, WBF, XQAQ, ipb, 1024, 1024, 1024, 2048, 0, 0, 0, 0, 0, 0, 1);
    // 2) XK = key @ W[2048:3072]^T + ipb[2048:3072]
    mfma_nt<128, 128, 0><<<dim3(8, 32, 1), blk, 0, stream>>>(
        KBF, WBF + 2097152, XK, ipb + 2048, 1024, 1024, 1024, 1024, 0, 0, 0, 0, 0, 0, 1);
    // 3) VT = transpose(val @ W[3072:4096]^T + ipb[3072:4096])
    mfma_nt<128, 128, 4><<<dim3(8, 32, 1), blk, 0, stream>>>(
        VBF, WBF + 3145728, VT, ipb + 3072, 1024, 1024, 1024, 0, 0, 0, 0, 0, 0, 0, 1);
    // 4) PHI[n][q][k] = tanh(xqa_q . xk_k) * CLAMP -> fp16
    mfma_nt<128, 128, 1><<<dim3(8, 4, 64), blk, 0, stream>>>(
        XQAQ, XK, PHI, nullptr, 64, 2048, 1024, 1024,
        512L * 2048, 64, 1024L * 1024, 64, 8388608L, 524288L, 16);

    // 5) chunked: DP -> reg scores -> softmax -> PV
    for (int c = 0; c < 4; ++c) {
        mono_dp_k<<<dim3(64), blk, 0, stream>>>(PHI, ALPHAC, STATE, c * 128);
        mfma_nt<128, 128, 2><<<dim3(8, 1, 64), blk, 0, stream>>>(
            XQAQ + 1024 + (long)c * 128 * 2048, XK, REGC, nullptr, 64, 2048, 1024, 1024,
            512L * 2048, 64, 1024L * 1024, 64, 2097152L, 131072L, 16);
        softmax_pk_k<<<dim3(8192), blk, 0, stream>>>(REGC, ALPHAC);
        mfma_nt<64, 64, 0><<<dim3(1, 2, 64), blk, 0, stream>>>(
            REGC, VT, XO + (long)c * 131072, nullptr, 1024, 1024, 1024, 1024,
            2097152L, 131072L, 1048576L, 65536L, 524288L, 64, 16);
    }

    // 6) out = XO @ ow^T + ob  (f32)
    mfma_nt<128, 128, 3><<<dim3(8, 16, 1), blk, 0, stream>>>(
        XO, OWBF, out, ob, 1024, 1024, 1024, 1024, 0, 0, 0, 0, 0, 0, 1);
}

// Round 4
// 421.060 us; speedup vs baseline: 3.4436x; 1.3006x over previous
//
#include <hip/hip_runtime.h>
#include <hip/hip_fp16.h>
#include <hip/hip_bf16.h>
#include <math.h>

typedef unsigned short u16;
typedef __attribute__((ext_vector_type(8))) short bf16x8;
typedef __attribute__((ext_vector_type(8))) unsigned short u16x8;
typedef __attribute__((ext_vector_type(4))) unsigned short u16x4;
typedef __attribute__((ext_vector_type(4))) float f32x4;

static constexpr float NEGF = -1e30f;
static constexpr float CLAMPF = 3.8918202981106265f; // -log(1/0.98 - 1)
static constexpr float SCALEF = 0.125f;              // 1/sqrt(64)
static constexpr float ASCALE = 16384.f;             // 2^14 alpha storage scale

__device__ __forceinline__ u16 f2bf(float x) {
    __hip_bfloat16 h = __float2bfloat16(x);
    return *reinterpret_cast<u16*>(&h);
}
__device__ __forceinline__ float bf2f(u16 b) {
    unsigned int u = ((unsigned int)b) << 16;
    return __uint_as_float(u);
}

// ---------------------------------------------------------------------------
// f32 -> bf16 conversion (vectorized 4/thread)
// ---------------------------------------------------------------------------
__global__ __launch_bounds__(256)
void cvt_f32_bf16_k(const float* __restrict__ src, u16* __restrict__ dst, int n4)
{
    int i = blockIdx.x * 256 + threadIdx.x;
    if (i < n4) {
        float4 v = ((const float4*)src)[i];
        u16x4 o; o.x = f2bf(v.x); o.y = f2bf(v.y); o.z = f2bf(v.z); o.w = f2bf(v.w);
        ((u16x4*)dst)[i] = o;
    }
}

// ---------------------------------------------------------------------------
// bf16 MFMA GEMM, NT form: C[m][n] = sum_k A[m][k]*B[n][k]  (+ epilogue)
// Tile TM x TN, BK=64, 256 threads = 4 waves in 2x2 grid, mfma_f32_16x16x32_bf16.
// EPI: 0=bf16(+opt bias), 1=fp16 sigmoid(CLAMP*tanh(x)), 2=bf16 *SCALE,
//      3=f32+bias, 4=bf16 V-transpose store (VT[(b*16+h)*64+d][k]) + bias
// ---------------------------------------------------------------------------
template<int TM, int TN, int EPI>
__global__ __launch_bounds__(256)
void mfma_nt(const u16* __restrict__ Ag, const u16* __restrict__ Bg,
             void* __restrict__ Cg, const float* __restrict__ bias,
             int K, int lda, int ldb, int ldc,
             long sAb, long sAh, long sBb, long sBh, long sCb, long sCh,
             int hdiv)
{
    __shared__ u16 As[TM * 64];
    __shared__ u16 Bs[TN * 64];

    int z = blockIdx.z;
    int b = z / hdiv, h = z % hdiv;
    const u16* A = Ag + (long)b * sAb + (long)h * sAh;
    const u16* B = Bg + (long)b * sBb + (long)h * sBh;

    int tid = threadIdx.x;
    int bm = blockIdx.y * TM, bn = blockIdx.x * TN;

    constexpr int AC = TM / 32;
    constexpr int BC = TN / 32;
    int srow = tid >> 3;          // 0..31
    int scol = (tid & 7) * 8;     // 0..56

    int wid = tid >> 6, lane = tid & 63;
    int wr = wid >> 1, wc = wid & 1;
    constexpr int MI = TM / 32;
    constexpr int NI = TN / 32;
    int arow0 = wr * (TM / 2) + (lane & 15);
    int bcol0 = wc * (TN / 2) + (lane & 15);
    int koff = (lane >> 4) * 8;

    f32x4 acc[MI][NI];
#pragma unroll
    for (int i = 0; i < MI; ++i)
#pragma unroll
        for (int j = 0; j < NI; ++j) acc[i][j] = (f32x4){0.f, 0.f, 0.f, 0.f};

    for (int kt = 0; kt < K; kt += 64) {
        u16x8 av[AC], bv[BC];
#pragma unroll
        for (int c = 0; c < AC; ++c)
            av[c] = *(const u16x8*)(A + (long)(bm + srow + 32 * c) * lda + kt + scol);
#pragma unroll
        for (int c = 0; c < BC; ++c)
            bv[c] = *(const u16x8*)(B + (long)(bn + srow + 32 * c) * ldb + kt + scol);
        __syncthreads();
#pragma unroll
        for (int c = 0; c < AC; ++c)
            *(u16x8*)&As[(srow + 32 * c) * 64 + scol] = av[c];
#pragma unroll
        for (int c = 0; c < BC; ++c)
            *(u16x8*)&Bs[(srow + 32 * c) * 64 + scol] = bv[c];
        __syncthreads();

#pragma unroll
        for (int ks = 0; ks < 2; ++ks) {
            bf16x8 af[MI], bfr[NI];
#pragma unroll
            for (int mi = 0; mi < MI; ++mi)
                af[mi] = *(const bf16x8*)&As[(arow0 + 16 * mi) * 64 + ks * 32 + koff];
#pragma unroll
            for (int ni = 0; ni < NI; ++ni)
                bfr[ni] = *(const bf16x8*)&Bs[(bcol0 + 16 * ni) * 64 + ks * 32 + koff];
#pragma unroll
            for (int mi = 0; mi < MI; ++mi)
#pragma unroll
                for (int ni = 0; ni < NI; ++ni)
                    acc[mi][ni] = __builtin_amdgcn_mfma_f32_16x16x32_bf16(
                        af[mi], bfr[ni], acc[mi][ni], 0, 0, 0);
        }
    }

    // Epilogue
    int rbase = bm + wr * (TM / 2) + (lane >> 4) * 4;
    int cbase = bn + wc * (TN / 2) + (lane & 15);
#pragma unroll
    for (int mi = 0; mi < MI; ++mi) {
#pragma unroll
        for (int ni = 0; ni < NI; ++ni) {
            int m0 = rbase + 16 * mi;
            int n = cbase + 16 * ni;
            if constexpr (EPI == 0) {
                u16* C = (u16*)Cg + (long)b * sCb + (long)h * sCh;
                float bvv = bias ? bias[n] : 0.f;
#pragma unroll
                for (int r = 0; r < 4; ++r)
                    C[(long)(m0 + r) * ldc + n] = f2bf(acc[mi][ni][r] + bvv);
            } else if constexpr (EPI == 1) {
                __half* C = (__half*)Cg + (long)b * sCb + (long)h * sCh;
#pragma unroll
                for (int r = 0; r < 4; ++r) {
                    float x = acc[mi][ni][r];
                    float e2 = __expf(2.f * x);
                    float tv = CLAMPF - (2.f * CLAMPF) / (e2 + 1.f);  // CLAMP*tanh(x)
                    float pv = 1.f / (1.f + __expf(-tv));             // sigmoid
                    C[(long)(m0 + r) * ldc + n] = __float2half(pv);
                }
            } else if constexpr (EPI == 2) {
                u16* C = (u16*)Cg + (long)b * sCb + (long)h * sCh;
#pragma unroll
                for (int r = 0; r < 4; ++r)
                    C[(long)(m0 + r) * ldc + n] = f2bf(acc[mi][ni][r] * SCALEF);
            } else if constexpr (EPI == 3) {
                float* C = (float*)Cg + (long)b * sCb + (long)h * sCh;
                float bvv = bias[n];
#pragma unroll
                for (int r = 0; r < 4; ++r)
                    C[(long)(m0 + r) * ldc + n] = acc[mi][ni][r] + bvv;
            } else { // EPI == 4: VT[(b16h)*64 + d][k] = V[m=b*1024+k][n=h*64+d]
                u16* C = (u16*)Cg;
                float bvv = bias[n];
                long vaddr = ((long)((m0 >> 10) * 16 + (n >> 6)) * 64 + (n & 63)) * 1024
                             + (m0 & 1023);
                u16x4 pk;
                pk.x = f2bf(acc[mi][ni][0] + bvv);
                pk.y = f2bf(acc[mi][ni][1] + bvv);
                pk.z = f2bf(acc[mi][ni][2] + bvv);
                pk.w = f2bf(acc[mi][ni][3] + bvv);
                *(u16x4*)(C + vaddr) = pk;
            }
        }
    }
}

// ---------------------------------------------------------------------------
// Monotonic DP, LINEAR probability domain (scaled by 2^14; mass-conserving so
// no rescaling needed). One WAVE per (b,h) slice; lane owns 16 contiguous k.
// a_new[i] = a[i]*p[i] + a[i-1]*(1-p[i-1]); shift via shfl_up. No LDS/barrier.
// Chunked over q (alpha cols [q0, q0+128)); f32 state carried in STATE.
// ---------------------------------------------------------------------------
struct pv16 { uint4 lo, hi; };

__device__ __forceinline__ pv16 dp_load(const __half* p, int col, int i0) {
    pv16 r;
    const uint4* src = (const uint4*)(p + (long)col * 1024 + i0);
    r.lo = src[0]; r.hi = src[1];
    return r;
}

#define DP_STEP(PC, J) do { \
    const __half2* hp = (const __half2*)&(PC); \
    float t[16], u[16]; \
    _Pragma("unroll") \
    for (int r8 = 0; r8 < 8; ++r8) { \
        float2 f = __half22float2(hp[r8]); \
        t[2 * r8]     = a[2 * r8]     * f.x; \
        t[2 * r8 + 1] = a[2 * r8 + 1] * f.y; \
    } \
    _Pragma("unroll") \
    for (int r = 0; r < 16; ++r) u[r] = a[r] - t[r]; \
    float up = __shfl_up(u[15], 1, 64); \
    if (lane == 0) up = 0.f; \
    a[0] = t[0] + up; \
    _Pragma("unroll") \
    for (int r = 1; r < 16; ++r) a[r] = t[r] + u[r - 1]; \
    uint4 o0, o1; \
    { __half2 h0 = __floats2half2_rn(a[0], a[1]),  h1 = __floats2half2_rn(a[2], a[3]); \
      __half2 h2 = __floats2half2_rn(a[4], a[5]),  h3 = __floats2half2_rn(a[6], a[7]); \
      o0.x = *(unsigned*)&h0; o0.y = *(unsigned*)&h1; o0.z = *(unsigned*)&h2; o0.w = *(unsigned*)&h3; \
      __half2 h4 = __floats2half2_rn(a[8], a[9]),  h5 = __floats2half2_rn(a[10], a[11]); \
      __half2 h6 = __floats2half2_rn(a[12], a[13]), h7 = __floats2half2_rn(a[14], a[15]); \
      o1.x = *(unsigned*)&h4; o1.y = *(unsigned*)&h5; o1.z = *(unsigned*)&h6; o1.w = *(unsigned*)&h7; } \
    uint4* dst = (uint4*)(al + (long)((J) - q0) * 1024 + i0); \
    dst[0] = o0; dst[1] = o1; \
} while (0)

__global__ __launch_bounds__(64)
void mono_dp_k(const __half* __restrict__ P, __half* __restrict__ AL,
               float* __restrict__ STATE, int q0)
{
    int n = blockIdx.x;
    int lane = threadIdx.x;                 // 0..63
    const __half* p = P + (long)n * 524288; // (512,1024) sigmoid probs
    __half* al = AL + (long)n * 131072;     // (128,1024) alpha chunk (scaled lin)
    float* stt = STATE + (long)n * 1024;
    int i0 = lane * 16;

    float a[16];
    if (q0 == 0) {
#pragma unroll
        for (int r = 0; r < 16; ++r) a[r] = 0.f;
        if (lane == 0) a[0] = ASCALE;
        // alpha column 0 = init distribution
        uint4 o0, o1;
        __half2 h0 = __floats2half2_rn(a[0], a[1]), h1 = __floats2half2_rn(a[2], a[3]);
        __half2 h2 = __floats2half2_rn(a[4], a[5]), h3 = __floats2half2_rn(a[6], a[7]);
        o0.x = *(unsigned*)&h0; o0.y = *(unsigned*)&h1; o0.z = *(unsigned*)&h2; o0.w = *(unsigned*)&h3;
        __half2 h4 = __floats2half2_rn(a[8], a[9]), h5 = __floats2half2_rn(a[10], a[11]);
        __half2 h6 = __floats2half2_rn(a[12], a[13]), h7 = __floats2half2_rn(a[14], a[15]);
        o1.x = *(unsigned*)&h4; o1.y = *(unsigned*)&h5; o1.z = *(unsigned*)&h6; o1.w = *(unsigned*)&h7;
        uint4* dst = (uint4*)(al + i0);
        dst[0] = o0; dst[1] = o1;
    } else {
#pragma unroll
        for (int r4 = 0; r4 < 4; ++r4) {
            float4 s = *(const float4*)(stt + i0 + 4 * r4);
            a[4 * r4 + 0] = s.x; a[4 * r4 + 1] = s.y;
            a[4 * r4 + 2] = s.z; a[4 * r4 + 3] = s.w;
        }
    }

    int jbeg = (q0 == 0) ? 1 : q0;
    int jend = q0 + 128;

    // depth-2 prefetch with statically named registers
    int j = jbeg;
    pv16 pA = dp_load(p, j - 1, i0);
    pv16 pB = dp_load(p, j, i0);
    while (j + 1 < jend) {
        DP_STEP(pA, j);
        pA = dp_load(p, min(j + 1, 511), i0);
        DP_STEP(pB, j + 1);
        pB = dp_load(p, min(j + 2, 511), i0);
        j += 2;
    }
    if (j < jend) DP_STEP(pA, j);

#pragma unroll
    for (int r4 = 0; r4 < 4; ++r4) {
        float4 s;
        s.x = a[4 * r4 + 0]; s.y = a[4 * r4 + 1];
        s.z = a[4 * r4 + 2]; s.w = a[4 * r4 + 3];
        *(float4*)(stt + i0 + 4 * r4) = s;
    }
}

// ---------------------------------------------------------------------------
// Row softmax over k with LINEAR alpha: w_k = a_k * exp(reg_k - max(reg)),
// P = w / sum(w). Scale of a cancels. bf16 scores in/out, fp16 alpha.
// ---------------------------------------------------------------------------
__global__ __launch_bounds__(256)
void softmax_pk_k(u16* __restrict__ P, const __half* __restrict__ A)
{
    long row = blockIdx.x;
    u16* rp = P + (row << 10);
    const __half* ap = A + (row << 10);
    int t = threadIdx.x;

    u16x4 s4 = ((const u16x4*)rp)[t];
    uint2 au = ((const uint2*)ap)[t];
    float2 fa01 = __half22float2(*(__half2*)&au.x);
    float2 fa23 = __half22float2(*(__half2*)&au.y);
    float r0 = bf2f(s4.x), r1 = bf2f(s4.y), r2 = bf2f(s4.z), r3 = bf2f(s4.w);

    float mx = fmaxf(fmaxf(r0, r1), fmaxf(r2, r3));
#pragma unroll
    for (int o = 1; o < 64; o <<= 1) mx = fmaxf(mx, __shfl_xor(mx, o, 64));
    __shared__ float redm[4], reds[4];
    int wave = t >> 6, lane = t & 63;
    if (lane == 0) redm[wave] = mx;
    __syncthreads();
    mx = fmaxf(fmaxf(redm[0], redm[1]), fmaxf(redm[2], redm[3]));

    float w0 = fa01.x * __expf(r0 - mx), w1 = fa01.y * __expf(r1 - mx);
    float w2 = fa23.x * __expf(r2 - mx), w3 = fa23.y * __expf(r3 - mx);
    float s = w0 + w1 + w2 + w3;
#pragma unroll
    for (int o = 1; o < 64; o <<= 1) s += __shfl_xor(s, o, 64);
    if (lane == 0) reds[wave] = s;
    __syncthreads();
    s = reds[0] + reds[1] + reds[2] + reds[3];
    float inv = 1.f / s;
    u16x4 o4; o4.x = f2bf(w0 * inv); o4.y = f2bf(w1 * inv);
    o4.z = f2bf(w2 * inv); o4.w = f2bf(w3 * inv);
    ((u16x4*)rp)[t] = o4;
}

// ---------------------------------------------------------------------------
extern "C" void kernel_launch(void* const* d_in, const int* in_sizes, int n_in,
                              void* d_out, int out_size, void* d_ws, size_t ws_size,
                              hipStream_t stream)
{
    const float* q   = (const float*)d_in[0];
    const float* key = (const float*)d_in[1];
    const float* val = (const float*)d_in[2];
    const float* W   = (const float*)d_in[3];
    const float* ipb = (const float*)d_in[4];
    const float* ow  = (const float*)d_in[5];
    const float* ob  = (const float*)d_in[6];
    float* out = (float*)d_out;
    char* w = (char*)d_ws;

    // Workspace layout (bytes). Total 126.25 MiB.
    __half* PSIG   = (__half*)(w);                 // 64 MiB  (64,512,1024) fp16 sigmoid(phi)
    __half* ALPHAC = (__half*)(w + 67108864);      // 16 MiB  (64,128,1024) fp16 linear alpha
    float*  STATE  = (float*)(w + 83886080);       // 256 KiB (64,1024) f32
    u16*    XQAQ   = (u16*)(w + 84148224);         // 8 MiB   (2048,2048) bf16
    u16*    XK     = (u16*)(w + 92536832);         // 8 MiB   (4096,1024) bf16
    u16*    VT     = (u16*)(w + 100925440);        // 8 MiB   (64,64,1024) bf16
    u16*    REGC   = (u16*)(w + 109314048);        // 16 MiB  (64,128,1024) bf16
    u16*    XO     = (u16*)(w + 126091264);        // 4 MiB   (2048,1024) bf16
    u16*    OWBF   = (u16*)(w + 130285568);        // 2 MiB   (1024,1024) bf16
    // Overlays inside PSIG region (dead before phi GEMM writes):
    u16* QBF = (u16*)(w);                          // 4 MiB
    u16* KBF = (u16*)(w + 4194304);                // 8 MiB
    u16* VBF = (u16*)(w + 12582912);               // 8 MiB
    u16* WBF = (u16*)(w + 20971520);               // 8 MiB

    dim3 blk(256);

    // 0) f32 -> bf16 copies
    cvt_f32_bf16_k<<<dim3(2048), blk, 0, stream>>>(q, QBF, 524288);
    cvt_f32_bf16_k<<<dim3(4096), blk, 0, stream>>>(key, KBF, 1048576);
    cvt_f32_bf16_k<<<dim3(4096), blk, 0, stream>>>(val, VBF, 1048576);
    cvt_f32_bf16_k<<<dim3(4096), blk, 0, stream>>>(W, WBF, 1048576);
    cvt_f32_bf16_k<<<dim3(1024), blk, 0, stream>>>(ow, OWBF, 262144);

    // 1) XQAQ = q @ W[0:2048]^T + ipb[0:2048]  (cols 0..1023 = xqa, 1024.. = xq)
    mfma_nt<128, 128, 0><<<dim3(16, 16, 1), blk, 0, stream>>>(
        QBF, WBF, XQAQ, ipb, 1024, 1024, 1024, 2048, 0, 0, 0, 0, 0, 0, 1);
    // 2) XK = key @ W[2048:3072]^T + ipb[2048:3072]
    mfma_nt<128, 128, 0><<<dim3(8, 32, 1), blk, 0, stream>>>(
        KBF, WBF + 2097152, XK, ipb + 2048, 1024, 1024, 1024, 1024, 0, 0, 0, 0, 0, 0, 1);
    // 3) VT = transpose(val @ W[3072:4096]^T + ipb[3072:4096])
    mfma_nt<128, 128, 4><<<dim3(8, 32, 1), blk, 0, stream>>>(
        VBF, WBF + 3145728, VT, ipb + 3072, 1024, 1024, 1024, 0, 0, 0, 0, 0, 0, 0, 1);
    // 4) PSIG[n][q][k] = sigmoid(CLAMP * tanh(xqa_q . xk_k)) -> fp16
    mfma_nt<128, 128, 1><<<dim3(8, 4, 64), blk, 0, stream>>>(
        XQAQ, XK, PSIG, nullptr, 64, 2048, 1024, 1024,
        512L * 2048, 64, 1024L * 1024, 64, 8388608L, 524288L, 16);

    // 5) chunked: DP -> reg scores -> softmax -> PV
    for (int c = 0; c < 4; ++c) {
        mono_dp_k<<<dim3(64), dim3(64), 0, stream>>>(PSIG, ALPHAC, STATE, c * 128);
        mfma_nt<128, 128, 2><<<dim3(8, 1, 64), blk, 0, stream>>>(
            XQAQ + 1024 + (long)c * 128 * 2048, XK, REGC, nullptr, 64, 2048, 1024, 1024,
            512L * 2048, 64, 1024L * 1024, 64, 2097152L, 131072L, 16);
        softmax_pk_k<<<dim3(8192), blk, 0, stream>>>(REGC, ALPHAC);
        mfma_nt<64, 64, 0><<<dim3(1, 2, 64), blk, 0, stream>>>(
            REGC, VT, XO + (long)c * 131072, nullptr, 1024, 1024, 1024, 1024,
            2097152L, 131072L, 1048576L, 65536L, 524288L, 64, 16);
    }

    // 6) out = XO @ ow^T + ob  (f32)
    mfma_nt<128, 128, 3><<<dim3(8, 16, 1), blk, 0, stream>>>(
        XO, OWBF, out, ob, 1024, 1024, 1024, 1024, 0, 0, 0, 0, 0, 0, 1);
}